// Round 8
// baseline (1351.758 us; speedup 1.0000x reference)
//
#include <hip/hip_runtime.h>

#define NN 100000   // nodes
#define NR 8        // relations
#define NE 200000   // edges per relation
#define NL 131072   // labels
#define NSEG (NR*NN)            // 800000 softmax segments
#define NB_SCAN 782             // ceil(800000/1024)
#define NPAD (NB_SCAN*1024)     // 800768 padded segment count

typedef __attribute__((ext_vector_type(8))) short short8;
typedef __attribute__((ext_vector_type(8))) _Float16 half8;
typedef __attribute__((ext_vector_type(4))) float floatx4;

__device__ __forceinline__ unsigned short f2h(float f) {
    _Float16 h = (_Float16)f;                   // RTN-even
    union { _Float16 h; unsigned short u; } c; c.h = h; return c.u;
}
__device__ __forceinline__ float h2f(unsigned short u) {
    union { _Float16 h; unsigned short u; } c; c.u = u; return (float)c.h;
}

// ---------- transpose 128x128 (w[k][j] -> wt[j][k]) ----------
__global__ void transpose128(const float* __restrict__ in, float* __restrict__ out) {
    int idx = blockIdx.x * 256 + threadIdx.x;   // 16384 total
    int j = idx >> 7, k = idx & 127;
    out[idx] = in[k * 128 + j];
}

// ---------- fp32 -> fp16 cast (count = grid*256*4 exactly; used for kw only) ----------
__global__ void cast_f16(const float* __restrict__ src, unsigned short* __restrict__ dst) {
    size_t idx = ((size_t)blockIdx.x * 256 + threadIdx.x) * 4;
    float4 v = *(const float4*)(src + idx);
    ushort4 o;
    o.x = f2h(v.x); o.y = f2h(v.y); o.z = f2h(v.z); o.w = f2h(v.w);
    *(ushort4*)(dst + idx) = o;
}

// ---------- CSR build: histogram over dst ----------
__global__ void hist_kernel(const int* __restrict__ ei, int* __restrict__ counts) {
    int idx = blockIdx.x * 256 + threadIdx.x;
    if (idx >= NR * NE) return;
    int r = idx / NE, e = idx - r * NE;
    int dst = ei[(size_t)r * 2 * NE + NE + e];
    atomicAdd(&counts[r * NN + dst], 1);
}

// ---------- scan k1 ----------
__global__ __launch_bounds__(256) void scan_k1(const int* __restrict__ counts,
                                               int* __restrict__ rowptr,
                                               int* __restrict__ bsums) {
    __shared__ int wsum[4];
    int t = threadIdx.x, lane = t & 63, w = t >> 6;
    int base = blockIdx.x * 1024 + t * 4;
    int c0 = counts[base], c1 = counts[base + 1], c2 = counts[base + 2], c3 = counts[base + 3];
    int s = c0 + c1 + c2 + c3;
    int inc = s;
#pragma unroll
    for (int off = 1; off < 64; off <<= 1) { int v = __shfl_up(inc, off); if (lane >= off) inc += v; }
    if (lane == 63) wsum[w] = inc;
    __syncthreads();
    int wbase = 0;
    for (int k = 0; k < w; ++k) wbase += wsum[k];
    int ex = wbase + inc - s;
    rowptr[base]     = ex;
    rowptr[base + 1] = ex + c0;
    rowptr[base + 2] = ex + c0 + c1;
    rowptr[base + 3] = ex + c0 + c1 + c2;
    if (t == 255) bsums[blockIdx.x] = wbase + inc;
}

// ---------- scan k2 ----------
__global__ __launch_bounds__(256) void scan_k2(int* __restrict__ bsums, int nb) {
    __shared__ int wsum[4];
    __shared__ int carry_s;
    int t = threadIdx.x, lane = t & 63, w = t >> 6;
    if (t == 0) carry_s = 0;
    __syncthreads();
    for (int base = 0; base < nb; base += 256) {
        int i = base + t;
        int v = (i < nb) ? bsums[i] : 0;
        int inc = v;
#pragma unroll
        for (int off = 1; off < 64; off <<= 1) { int u = __shfl_up(inc, off); if (lane >= off) inc += u; }
        if (lane == 63) wsum[w] = inc;
        __syncthreads();
        int wbase = carry_s;
        for (int k = 0; k < w; ++k) wbase += wsum[k];
        if (i < nb) bsums[i] = wbase + inc - v;
        __syncthreads();
        if (t == 0) carry_s += wsum[0] + wsum[1] + wsum[2] + wsum[3];
        __syncthreads();
    }
}

// ---------- scan k3 ----------
__global__ void scan_k3(int* __restrict__ rowptr, const int* __restrict__ bsums) {
    int i = blockIdx.x * 256 + threadIdx.x;
    if (i <= NSEG) rowptr[i] += bsums[i >> 10];
}

// ---------- CSR fill: es[pos].x = src (dst-sorted); .y filled by softmax ----------
__global__ void fill_kernel(const int* __restrict__ ei, const int* __restrict__ rowptr,
                            int* __restrict__ cursor, int* __restrict__ es_raw) {
    int idx = blockIdx.x * 256 + threadIdx.x;
    if (idx >= NR * NE) return;
    int r = idx / NE, e = idx - r * NE;
    int src = ei[(size_t)r * 2 * NE + e];
    int dst = ei[(size_t)r * 2 * NE + NE + e];
    int g = r * NN + dst;
    int pos = rowptr[g] + atomicAdd(&cursor[g], 1);
    es_raw[2 * pos] = src;
}

// ---------- proj GEMM (fp32 vector; despilled per round-2 lesson) ----------
__global__ __launch_bounds__(256, 3) void gemm_proj(
    const float* __restrict__ A, const float* __restrict__ B,
    const float* __restrict__ bias, float* __restrict__ out, int nrows)
{
    __shared__ float As[128][36];
    __shared__ float Bs[128][36];
    const int tid = threadIdx.x;
    const int row0 = blockIdx.x * 128;
    const int cg = tid & 15;
    const int nb = (tid >> 4) * 8;

    float acc[8][8];
#pragma unroll
    for (int i = 0; i < 8; ++i)
#pragma unroll
        for (int j = 0; j < 8; ++j) acc[i][j] = 0.f;

    for (int k0 = 0; k0 < 128; k0 += 32) {
#pragma unroll
        for (int i = 0; i < 4; ++i) {
            int fi = tid + i * 256;
            int rw = fi >> 3, kq = fi & 7;
            int n = row0 + rw;
            float4 v = make_float4(0.f, 0.f, 0.f, 0.f);
            if (n < nrows) v = *(const float4*)(A + (size_t)n * 128 + k0 + kq * 4);
            *(float4*)&As[rw][kq * 4] = v;
            float4 w = *(const float4*)(B + rw * 128 + k0 + kq * 4);
            *(float4*)&Bs[rw][kq * 4] = w;
        }
        __syncthreads();
#pragma unroll 2
        for (int kq = 0; kq < 8; ++kq) {
            float4 wv[8];
#pragma unroll
            for (int j = 0; j < 8; ++j) wv[j] = *(const float4*)&Bs[cg + 16 * j][kq * 4];
#pragma unroll
            for (int i = 0; i < 8; ++i) {
                float4 xv = *(const float4*)&As[nb + i][kq * 4];
#pragma unroll
                for (int j = 0; j < 8; ++j)
                    acc[i][j] += xv.x * wv[j].x + xv.y * wv[j].y
                               + xv.z * wv[j].z + xv.w * wv[j].w;
            }
        }
        __syncthreads();
    }
#pragma unroll
    for (int i = 0; i < 8; ++i) {
        int n = row0 + nb + i;
        if (n < nrows) {
#pragma unroll
            for (int j = 0; j < 8; ++j) {
                int d = cg + 16 * j;
                out[(size_t)n * 128 + d] = acc[i][j] + bias[d];
            }
        }
    }
}

// ---------- fused gather(LDS) + MFMA semantic-score GEMM (fp16 table) ----------
// 4-wide clamped edge loop: indices past p1 clamp to p0 with alpha=0 --
// uniform iteration count, 8 independent line loads in flight (MLP=8 lines).
// Full-line gather: lane l reads dims [l*8,+8) (line 0) and [64+l*8,+8) (line 1).
__global__ __launch_bounds__(256) void fused_score2(
    const int* __restrict__ rowptr, const int2* __restrict__ es,
    const unsigned short* __restrict__ h16,
    const unsigned short* __restrict__ kw16, const float* __restrict__ kb,
    const float* __restrict__ q, float* __restrict__ scorebuf)
{
    __shared__ unsigned short Os[64][136];   // 17.4 KB; 272 B rows (fp16)
    __shared__ float redbuf[4];
    const int t = threadIdx.x;
    const int r = blockIdx.y;
    const int row0 = blockIdx.x * 64;        // grid.x 1563 -> 100032
    const int l = t & 7, ng = t >> 3;        // lane dim-slot / node group

#pragma unroll
    for (int pass = 0; pass < 2; ++pass) {
        int nl = pass * 32 + ng;
        int n = row0 + nl;
        float acc[16];
#pragma unroll
        for (int i = 0; i < 16; ++i) acc[i] = 0.f;
        if (n < NN) {
            int g = r * NN + n;
            int p0 = rowptr[g], p1 = rowptr[g + 1];
            for (int e = p0; e < p1; e += 4) {
                int i1 = (e + 1 < p1) ? e + 1 : p0;
                int i2 = (e + 2 < p1) ? e + 2 : p0;
                int i3 = (e + 3 < p1) ? e + 3 : p0;
                int2 e0 = es[e], e1 = es[i1], e2 = es[i2], e3 = es[i3];
                float a0 = __int_as_float(e0.y);
                float a1 = (e + 1 < p1) ? __int_as_float(e1.y) : 0.f;
                float a2 = (e + 2 < p1) ? __int_as_float(e2.y) : 0.f;
                float a3 = (e + 3 < p1) ? __int_as_float(e3.y) : 0.f;
                const unsigned short* hp0 = h16 + (size_t)e0.x * 128;
                const unsigned short* hp1 = h16 + (size_t)e1.x * 128;
                const unsigned short* hp2 = h16 + (size_t)e2.x * 128;
                const unsigned short* hp3 = h16 + (size_t)e3.x * 128;
                short8 x00 = *(const short8*)(hp0 + l * 8);
                short8 x01 = *(const short8*)(hp0 + 64 + l * 8);
                short8 x10 = *(const short8*)(hp1 + l * 8);
                short8 x11 = *(const short8*)(hp1 + 64 + l * 8);
                short8 x20 = *(const short8*)(hp2 + l * 8);
                short8 x21 = *(const short8*)(hp2 + 64 + l * 8);
                short8 x30 = *(const short8*)(hp3 + l * 8);
                short8 x31 = *(const short8*)(hp3 + 64 + l * 8);
#pragma unroll
                for (int i = 0; i < 8; ++i)
                    acc[i]     += a0 * h2f((unsigned short)x00[i]) + a1 * h2f((unsigned short)x10[i])
                                + a2 * h2f((unsigned short)x20[i]) + a3 * h2f((unsigned short)x30[i]);
#pragma unroll
                for (int i = 0; i < 8; ++i)
                    acc[8 + i] += a0 * h2f((unsigned short)x01[i]) + a1 * h2f((unsigned short)x11[i])
                                + a2 * h2f((unsigned short)x21[i]) + a3 * h2f((unsigned short)x31[i]);
            }
        }
        unsigned short ov[16];
#pragma unroll
        for (int i = 0; i < 16; ++i) ov[i] = f2h(fmaxf(acc[i], 0.f));  // relu
        // lane l owns dims [l*8, l*8+8) and [64+l*8, ...): dim-major Os
        *(short8*)&Os[nl][l * 8]      = *(short8*)&ov[0];
        *(short8*)&Os[nl][64 + l * 8] = *(short8*)&ov[8];
    }
    __syncthreads();

    // MFMA (f16): wave w owns rows w*16..w*16+15. A[m=lane&15][k=quad*8+j]
    // (m89 layout, shape-determined); C/D: col=lane&15, row=quad*4+reg.
    const int wave = t >> 6, lane = t & 63;
    const int quad = lane >> 4, l16 = lane & 15;
    half8 a[4];
#pragma unroll
    for (int kc = 0; kc < 4; ++kc)
        a[kc] = *(const half8*)&Os[wave * 16 + l16][quad * 8 + kc * 32];

    float s = 0.f;
#pragma unroll
    for (int dt = 0; dt < 8; ++dt) {
        const unsigned short* brow = kw16 + (size_t)(dt * 16 + l16) * 128 + quad * 8;
        floatx4 accv = {0.f, 0.f, 0.f, 0.f};
#pragma unroll
        for (int kc = 0; kc < 4; ++kc) {
            half8 b = *(const half8*)(brow + kc * 32);
            accv = __builtin_amdgcn_mfma_f32_16x16x32_f16(a[kc], b, accv, 0, 0, 0);
        }
        int d = dt * 16 + l16;
        float kbv = kb[d], qv = q[d];
#pragma unroll
        for (int reg = 0; reg < 4; ++reg) {
            int node = row0 + wave * 16 + quad * 4 + reg;
            if (node < NN) {
                float y = accv[reg] + kbv;
                float e2 = __expf(2.f * y);
                float tn = 1.f - 2.f * __builtin_amdgcn_rcpf(e2 + 1.f);   // tanh
                s += tn * qv;
            }
        }
    }
    for (int off = 32; off > 0; off >>= 1) s += __shfl_down(s, off);
    if (lane == 0) redbuf[wave] = s;
    __syncthreads();
    if (t == 0) atomicAdd(scorebuf + r * 64 + (blockIdx.x & 63),
                          redbuf[0] + redbuf[1] + redbuf[2] + redbuf[3]);
}

// ---------- reduce 64 score partials per relation (1 wave) ----------
__global__ void score_reduce(const float* __restrict__ scorebuf, float* __restrict__ score) {
    int t = threadIdx.x;              // <<<1, 64>>>
    int r = t >> 3, k = t & 7;
    float v = 0.f;
#pragma unroll
    for (int i = 0; i < 8; ++i) v += scorebuf[r * 64 + k * 8 + i];
    v += __shfl_down(v, 4);
    v += __shfl_down(v, 2);
    v += __shfl_down(v, 1);
    if (k == 0) score[r] = v;
}

// ---------- per-node attention logits + fused fp16 h emit ----------
__global__ __launch_bounds__(256) void att_kernel(
    const float* __restrict__ h, const float* __restrict__ asrc_w,
    const float* __restrict__ adst_w, float* __restrict__ a_src,
    float* __restrict__ a_dst, unsigned short* __restrict__ h16)
{
    __shared__ float hs[16][128];
    int n0 = blockIdx.x * 16;
#pragma unroll
    for (int i = 0; i < 2; ++i) {
        int fi = threadIdx.x + i * 256;
        int n = fi >> 5, kq = fi & 31;
        float4 v = make_float4(0.f, 0.f, 0.f, 0.f);
        if (n0 + n < NN) v = *(const float4*)(h + (size_t)(n0 + n) * 128 + kq * 4);
        *(float4*)&hs[n][kq * 4] = v;
    }
    __syncthreads();
    int n = threadIdx.x >> 4, rr = threadIdx.x & 15;
    int r = rr & 7; int isd = rr >> 3;
    const float* w = (isd ? adst_w : asrc_w) + r * 128;
    float acc = 0.f;
#pragma unroll
    for (int kq = 0; kq < 32; ++kq) {
        float4 hv = *(const float4*)&hs[n][kq * 4];
        float4 wv = ((const float4*)w)[kq];
        acc += hv.x * wv.x + hv.y * wv.y + hv.z * wv.z + hv.w * wv.w;
    }
    if (n0 + n < NN) (isd ? a_dst : a_src)[r * NN + n0 + n] = acc;

    // emit fp16 copy of this node tile (h already staged -- saves a 51 MB pass)
    int dq = rr * 8;
    if (n0 + n < NN) {
        unsigned short ov[8];
#pragma unroll
        for (int k = 0; k < 8; ++k) ov[k] = f2h(hs[n][dq + k]);
        *(short8*)(h16 + (size_t)(n0 + n) * 128 + dq) = *(short8*)ov;
    }
}

// ---------- CSR segment softmax (PyG semantics, +1e-16); alpha -> es[].y ----------
// deg<=16: fully-unrolled predicated register pass (16 independent gathers,
// static indices -> VGPRs; bit-identical to the 3-pass path). deg>16: fallback.
__global__ void softmax_csr(const int* __restrict__ rowptr, int2* __restrict__ es,
                            const float* __restrict__ a_src, const float* __restrict__ a_dst)
{
    int g = blockIdx.x * 256 + threadIdx.x;
    if (g >= NSEG) return;
    int p0 = rowptr[g], p1 = rowptr[g + 1];
    int deg = p1 - p0;
    if (deg == 0) return;
    int r = g / NN;
    float ad = a_dst[g];
    const float* as = a_src + (size_t)r * NN;
    if (deg <= 16) {
        float lg[16];
        float m = -1e30f;
#pragma unroll
        for (int i = 0; i < 16; ++i) {
            if (i < deg) {
                float l = as[es[p0 + i].x] + ad;
                l = l > 0.f ? l : 0.2f * l;   // leaky_relu 0.2
                lg[i] = l;
                m = fmaxf(m, l);
            }
        }
        float ssum = 0.f;
#pragma unroll
        for (int i = 0; i < 16; ++i) {
            if (i < deg) { float ex = __expf(lg[i] - m); lg[i] = ex; ssum += ex; }
        }
        float inv = __builtin_amdgcn_rcpf(ssum + 1e-16f);
#pragma unroll
        for (int i = 0; i < 16; ++i) {
            if (i < deg) es[p0 + i].y = __float_as_int(lg[i] * inv);
        }
    } else {
        float m = -1e30f;
        for (int i = p0; i < p1; ++i) {
            float l = as[es[i].x] + ad;
            l = l > 0.f ? l : 0.2f * l;
            es[i].y = __float_as_int(l);
            m = fmaxf(m, l);
        }
        float s = 0.f;
        for (int k = p0; k < p1; ++k) {
            float e = __expf(__int_as_float(es[k].y) - m);
            es[k].y = __float_as_int(e);
            s += e;
        }
        float inv = __builtin_amdgcn_rcpf(s + 1e-16f);
        for (int k = p0; k < p1; ++k)
            es[k].y = __float_as_int(__int_as_float(es[k].y) * inv);
    }
}

// ---------- combine: fp16 gather, 4-wide clamped loop, fp32 accumulate ----------
// Full-line: lane (o = L&7) reads 16B at dims [o*8,+8) and [64+o*8,+8).
__global__ __launch_bounds__(256) void combine_csr(
    const int* __restrict__ rowptr, const int2* __restrict__ es,
    const unsigned short* __restrict__ h16, const float* __restrict__ score,
    float* __restrict__ comb)
{
    __shared__ float attn[NR];
    __shared__ float lds[4][64][17];          // 17.4 KB
    int t = threadIdx.x;
    if (t == 0) {
        float sc[NR]; float m = -1e30f;
        for (int r = 0; r < NR; ++r) { sc[r] = score[r] * (1.0f / NN); m = fmaxf(m, sc[r]); }
        float den = 0.f;
        for (int r = 0; r < NR; ++r) { sc[r] = __expf(sc[r] - m); den += sc[r]; }
        for (int r = 0; r < NR; ++r) attn[r] = sc[r] / den;
    }
    __syncthreads();

    int nl = t >> 6;
    int n = blockIdx.x * 4 + nl;              // grid 25000 -> n < 100000 exactly
    int L = t & 63;
    int r = L >> 3;
    int o = L & 7;                            // owns dims [o*8,+8) and [64+o*8,+8)
    float a[16];
#pragma unroll
    for (int i = 0; i < 16; ++i) a[i] = 0.f;
    {
        int g = r * NN + n;
        int p0 = rowptr[g], p1 = rowptr[g + 1];
        for (int e = p0; e < p1; e += 4) {
            int i1 = (e + 1 < p1) ? e + 1 : p0;
            int i2 = (e + 2 < p1) ? e + 2 : p0;
            int i3 = (e + 3 < p1) ? e + 3 : p0;
            int2 e0 = es[e], e1 = es[i1], e2 = es[i2], e3 = es[i3];
            float a0 = __int_as_float(e0.y);
            float a1 = (e + 1 < p1) ? __int_as_float(e1.y) : 0.f;
            float a2 = (e + 2 < p1) ? __int_as_float(e2.y) : 0.f;
            float a3 = (e + 3 < p1) ? __int_as_float(e3.y) : 0.f;
            const unsigned short* hp0 = h16 + (size_t)e0.x * 128;
            const unsigned short* hp1 = h16 + (size_t)e1.x * 128;
            const unsigned short* hp2 = h16 + (size_t)e2.x * 128;
            const unsigned short* hp3 = h16 + (size_t)e3.x * 128;
            short8 x00 = *(const short8*)(hp0 + o * 8);
            short8 x01 = *(const short8*)(hp0 + 64 + o * 8);
            short8 x10 = *(const short8*)(hp1 + o * 8);
            short8 x11 = *(const short8*)(hp1 + 64 + o * 8);
            short8 x20 = *(const short8*)(hp2 + o * 8);
            short8 x21 = *(const short8*)(hp2 + 64 + o * 8);
            short8 x30 = *(const short8*)(hp3 + o * 8);
            short8 x31 = *(const short8*)(hp3 + 64 + o * 8);
#pragma unroll
            for (int i = 0; i < 8; ++i) {
                a[i]     += a0 * h2f((unsigned short)x00[i]) + a1 * h2f((unsigned short)x10[i])
                          + a2 * h2f((unsigned short)x20[i]) + a3 * h2f((unsigned short)x30[i]);
                a[8 + i] += a0 * h2f((unsigned short)x01[i]) + a1 * h2f((unsigned short)x11[i])
                          + a2 * h2f((unsigned short)x21[i]) + a3 * h2f((unsigned short)x31[i]);
            }
        }
    }
    float w = attn[r];
    float* dst = &lds[nl][L][0];
#pragma unroll
    for (int i = 0; i < 16; ++i) dst[i] = w * fmaxf(a[i], 0.f);   // relu per (n,r)
    __syncthreads();

    // phase 2: sum over relations. Lane (r,o) slot s holds dim o*8+s (s<8) or
    // 64+o*8+(s-8) (s>=8). Thread L writes dims d0=2L, d0+1 (same o, s pair).
    int d0 = 2 * L;
    int o2, s0;
    if (d0 < 64) { o2 = d0 >> 3; s0 = d0 & 7; }
    else         { o2 = (d0 - 64) >> 3; s0 = 8 + ((d0 - 64) & 7); }
    float x0 = 0.f, x1 = 0.f;
#pragma unroll
    for (int rr = 0; rr < NR; ++rr) {
        x0 += lds[nl][rr * 8 + o2][s0];
        x1 += lds[nl][rr * 8 + o2][s0 + 1];
    }
    *(float2*)(comb + (size_t)n * 128 + d0) = make_float2(x0, x1);
}

// ---------- link head ----------
__global__ __launch_bounds__(256) void head_kernel(
    const float* __restrict__ hfin, const int* __restrict__ eli,
    const float* __restrict__ pw, const float* __restrict__ pb,
    float* __restrict__ out)
{
    int t = threadIdx.x;
    int l = blockIdx.x * 4 + (t >> 6);        // grid 32768 -> l < 131072 exactly
    int d0 = (t & 63) * 2;
    int a = eli[l], b = eli[NL + l];
    float2 ha = *(const float2*)(hfin + (size_t)a * 128 + d0);
    float2 hb = *(const float2*)(hfin + (size_t)b * 128 + d0);
    float w0 = pw[d0 * 2] + pw[d0 * 2 + 1];
    float w1 = pw[d0 * 2 + 2] + pw[d0 * 2 + 3];
    float v = ha.x * hb.x * w0 + ha.y * hb.y * w1;
    for (int off = 32; off > 0; off >>= 1) v += __shfl_down(v, off);
    if ((t & 63) == 0) out[l] = v + pb[0] + pb[1];
}

extern "C" void kernel_launch(void* const* d_in, const int* in_sizes, int n_in,
                              void* d_out, int out_size, void* d_ws, size_t ws_size,
                              hipStream_t stream)
{
    const float* x     = (const float*)d_in[0];
    const int*   ei    = (const int*)d_in[1];
    const int*   eli   = (const int*)d_in[2];
    const float* w1    = (const float*)d_in[3];
    const float* b1    = (const float*)d_in[4];
    const float* asrc1 = (const float*)d_in[5];
    const float* adst1 = (const float*)d_in[6];
    const float* q1    = (const float*)d_in[7];
    const float* kw1   = (const float*)d_in[8];
    const float* kb1   = (const float*)d_in[9];
    const float* w2    = (const float*)d_in[10];
    const float* b2    = (const float*)d_in[11];
    const float* asrc2 = (const float*)d_in[12];
    const float* adst2 = (const float*)d_in[13];
    const float* q2    = (const float*)d_in[14];
    const float* kw2   = (const float*)d_in[15];
    const float* kb2   = (const float*)d_in[16];
    const float* pw    = (const float*)d_in[17];
    const float* pb    = (const float*)d_in[18];
    float* out = (float*)d_out;

    // ---- workspace layout (float offsets); total ~128.2 MB ----
    float* ws      = (float*)d_ws;
    float* hA      = ws;                         // 12,800,000
    float* hB      = ws + 12800000ull;           // 12,800,000
    float* a_src   = ws + 25600000ull;           // 800,000
    float* a_dst   = ws + 26400000ull;           // 800,000
    int2*  es      = (int2*)(ws + 27200000ull);  // 1,600,000 x int2 (src, alpha)
    int*   rowptr  = (int*)(ws + 30400000ull);   // 800,768 (padded)
    int*   counts  = (int*)(ws + 31200768ull);   // 800,768 (padded; reused as cursor)
    int*   bsums   = (int*)(ws + 32001536ull);   // 1,024
    float* score   = ws + 32002560ull;           // 64
    float* wt      = ws + 32002624ull;           // 16,384
    unsigned short* kw16 = (unsigned short*)(ws + 32019008ull);  // 16,384 ushorts
    // scorebuf (512 floats) aliases counts: counts/cursor dead after fill_kernel
    float* scorebuf = (float*)counts;
    // Ping-pong per layer: H (fp32 h, then overwritten by comb) and the fp16
    // table h16 live in opposite halves. All reuse is stream-ordered:
    //   L0: gemm x->hA;  h16 in hB;  comb -> hA (h fp32 dead after att)
    //   L1: gemm hA->hB; h16 in hA (comb0 dead after gemm); comb -> hB
    // head reads hB.

    // ---- CSR build (edge_index is layer-invariant: build once) ----
    hipMemsetAsync(counts, 0, NPAD * sizeof(int), stream);
    hist_kernel<<<6250, 256, 0, stream>>>(ei, counts);
    scan_k1<<<NB_SCAN, 256, 0, stream>>>(counts, rowptr, bsums);
    scan_k2<<<1, 256, 0, stream>>>(bsums, NB_SCAN);
    scan_k3<<<3126, 256, 0, stream>>>(rowptr, bsums);
    hipMemsetAsync(counts, 0, NPAD * sizeof(int), stream);
    fill_kernel<<<6250, 256, 0, stream>>>(ei, rowptr, counts, (int*)es);

    for (int layer = 0; layer < 2; ++layer) {
        const float* Ain  = layer ? hA : x;
        float*       H    = layer ? hB : hA;
        unsigned short* h16 = (unsigned short*)(layer ? hA : hB);
        const float* W    = layer ? w2 : w1;
        const float* bb   = layer ? b2 : b1;
        const float* as_w = layer ? asrc2 : asrc1;
        const float* ad_w = layer ? adst2 : adst1;
        const float* qq   = layer ? q2 : q1;
        const float* kw   = layer ? kw2 : kw1;
        const float* kb   = layer ? kb2 : kb1;

        transpose128<<<64, 256, 0, stream>>>(W, wt);
        gemm_proj<<<782, 256, 0, stream>>>(Ain, wt, bb, H, NN);
        cast_f16<<<16, 256, 0, stream>>>(kw, kw16);
        att_kernel<<<6250, 256, 0, stream>>>(H, as_w, ad_w, a_src, a_dst, h16);
        softmax_csr<<<3125, 256, 0, stream>>>(rowptr, es, a_src, a_dst);
        hipMemsetAsync(scorebuf, 0, 512 * sizeof(float), stream);
        fused_score2<<<dim3(1563, NR), 256, 0, stream>>>(rowptr, es, h16,
                                                         kw16, kb, qq, scorebuf);
        score_reduce<<<1, 64, 0, stream>>>(scorebuf, score);
        combine_csr<<<25000, 256, 0, stream>>>(rowptr, es, h16, score, H);
        // H now holds this layer's output embeddings (comb)
    }
    head_kernel<<<32768, 256, 0, stream>>>(hB, eli, pw, pb, out);
}

// Round 9
// 1280.885 us; speedup vs baseline: 1.0553x; 1.0553x over previous
//
#include <hip/hip_runtime.h>
#include <hip/hip_fp8.h>

#define NN 100000   // nodes
#define NR 8        // relations
#define NE 200000   // edges per relation
#define NL 131072   // labels
#define NSEG (NR*NN)            // 800000 softmax segments
#define NB_SCAN 782             // ceil(800000/1024)
#define NPAD (NB_SCAN*1024)     // 800768 padded segment count

typedef __attribute__((ext_vector_type(8))) short short8;
typedef __attribute__((ext_vector_type(8))) _Float16 half8;
typedef __attribute__((ext_vector_type(4))) float floatx4;

__device__ __forceinline__ unsigned short f2h(float f) {
    _Float16 h = (_Float16)f;                   // RTN-even
    union { _Float16 h; unsigned short u; } c; c.h = h; return c.u;
}
__device__ __forceinline__ float h2f(unsigned short u) {
    union { _Float16 h; unsigned short u; } c; c.u = u; return (float)c.h;
}
__device__ __forceinline__ unsigned fp8enc(float f) {      // e4m3fn, saturating
    __hip_fp8_e4m3 t(f); return (unsigned)t.__x;
}
__device__ __forceinline__ float fp8dec(unsigned b) {
    __hip_fp8_e4m3 t; t.__x = (__hip_fp8_storage_t)b; return (float)t;
}

// ---------- transpose 128x128 (w[k][j] -> wt[j][k]) ----------
__global__ void transpose128(const float* __restrict__ in, float* __restrict__ out) {
    int idx = blockIdx.x * 256 + threadIdx.x;   // 16384 total
    int j = idx >> 7, k = idx & 127;
    out[idx] = in[k * 128 + j];
}

// ---------- fp32 -> fp16 cast (count = grid*256*4 exactly; used for kw only) ----------
__global__ void cast_f16(const float* __restrict__ src, unsigned short* __restrict__ dst) {
    size_t idx = ((size_t)blockIdx.x * 256 + threadIdx.x) * 4;
    float4 v = *(const float4*)(src + idx);
    ushort4 o;
    o.x = f2h(v.x); o.y = f2h(v.y); o.z = f2h(v.z); o.w = f2h(v.w);
    *(ushort4*)(dst + idx) = o;
}

// ---------- CSR build: histogram over dst ----------
__global__ void hist_kernel(const int* __restrict__ ei, int* __restrict__ counts) {
    int idx = blockIdx.x * 256 + threadIdx.x;
    if (idx >= NR * NE) return;
    int r = idx / NE, e = idx - r * NE;
    int dst = ei[(size_t)r * 2 * NE + NE + e];
    atomicAdd(&counts[r * NN + dst], 1);
}

// ---------- scan k1 ----------
__global__ __launch_bounds__(256) void scan_k1(const int* __restrict__ counts,
                                               int* __restrict__ rowptr,
                                               int* __restrict__ bsums) {
    __shared__ int wsum[4];
    int t = threadIdx.x, lane = t & 63, w = t >> 6;
    int base = blockIdx.x * 1024 + t * 4;
    int c0 = counts[base], c1 = counts[base + 1], c2 = counts[base + 2], c3 = counts[base + 3];
    int s = c0 + c1 + c2 + c3;
    int inc = s;
#pragma unroll
    for (int off = 1; off < 64; off <<= 1) { int v = __shfl_up(inc, off); if (lane >= off) inc += v; }
    if (lane == 63) wsum[w] = inc;
    __syncthreads();
    int wbase = 0;
    for (int k = 0; k < w; ++k) wbase += wsum[k];
    int ex = wbase + inc - s;
    rowptr[base]     = ex;
    rowptr[base + 1] = ex + c0;
    rowptr[base + 2] = ex + c0 + c1;
    rowptr[base + 3] = ex + c0 + c1 + c2;
    if (t == 255) bsums[blockIdx.x] = wbase + inc;
}

// ---------- scan k2 ----------
__global__ __launch_bounds__(256) void scan_k2(int* __restrict__ bsums, int nb) {
    __shared__ int wsum[4];
    __shared__ int carry_s;
    int t = threadIdx.x, lane = t & 63, w = t >> 6;
    if (t == 0) carry_s = 0;
    __syncthreads();
    for (int base = 0; base < nb; base += 256) {
        int i = base + t;
        int v = (i < nb) ? bsums[i] : 0;
        int inc = v;
#pragma unroll
        for (int off = 1; off < 64; off <<= 1) { int u = __shfl_up(inc, off); if (lane >= off) inc += u; }
        if (lane == 63) wsum[w] = inc;
        __syncthreads();
        int wbase = carry_s;
        for (int k = 0; k < w; ++k) wbase += wsum[k];
        if (i < nb) bsums[i] = wbase + inc - v;
        __syncthreads();
        if (t == 0) carry_s += wsum[0] + wsum[1] + wsum[2] + wsum[3];
        __syncthreads();
    }
}

// ---------- scan k3 ----------
__global__ void scan_k3(int* __restrict__ rowptr, const int* __restrict__ bsums) {
    int i = blockIdx.x * 256 + threadIdx.x;
    if (i <= NSEG) rowptr[i] += bsums[i >> 10];
}

// ---------- CSR fill: es[pos].x = src (dst-sorted); .y filled by softmax ----------
__global__ void fill_kernel(const int* __restrict__ ei, const int* __restrict__ rowptr,
                            int* __restrict__ cursor, int* __restrict__ es_raw) {
    int idx = blockIdx.x * 256 + threadIdx.x;
    if (idx >= NR * NE) return;
    int r = idx / NE, e = idx - r * NE;
    int src = ei[(size_t)r * 2 * NE + e];
    int dst = ei[(size_t)r * 2 * NE + NE + e];
    int g = r * NN + dst;
    int pos = rowptr[g] + atomicAdd(&cursor[g], 1);
    es_raw[2 * pos] = src;
}

// ---------- proj GEMM (fp32 vector; despilled per round-2 lesson) ----------
__global__ __launch_bounds__(256, 3) void gemm_proj(
    const float* __restrict__ A, const float* __restrict__ B,
    const float* __restrict__ bias, float* __restrict__ out, int nrows)
{
    __shared__ float As[128][36];
    __shared__ float Bs[128][36];
    const int tid = threadIdx.x;
    const int row0 = blockIdx.x * 128;
    const int cg = tid & 15;
    const int nb = (tid >> 4) * 8;

    float acc[8][8];
#pragma unroll
    for (int i = 0; i < 8; ++i)
#pragma unroll
        for (int j = 0; j < 8; ++j) acc[i][j] = 0.f;

    for (int k0 = 0; k0 < 128; k0 += 32) {
#pragma unroll
        for (int i = 0; i < 4; ++i) {
            int fi = tid + i * 256;
            int rw = fi >> 3, kq = fi & 7;
            int n = row0 + rw;
            float4 v = make_float4(0.f, 0.f, 0.f, 0.f);
            if (n < nrows) v = *(const float4*)(A + (size_t)n * 128 + k0 + kq * 4);
            *(float4*)&As[rw][kq * 4] = v;
            float4 w = *(const float4*)(B + rw * 128 + k0 + kq * 4);
            *(float4*)&Bs[rw][kq * 4] = w;
        }
        __syncthreads();
#pragma unroll 2
        for (int kq = 0; kq < 8; ++kq) {
            float4 wv[8];
#pragma unroll
            for (int j = 0; j < 8; ++j) wv[j] = *(const float4*)&Bs[cg + 16 * j][kq * 4];
#pragma unroll
            for (int i = 0; i < 8; ++i) {
                float4 xv = *(const float4*)&As[nb + i][kq * 4];
#pragma unroll
                for (int j = 0; j < 8; ++j)
                    acc[i][j] += xv.x * wv[j].x + xv.y * wv[j].y
                               + xv.z * wv[j].z + xv.w * wv[j].w;
            }
        }
        __syncthreads();
    }
#pragma unroll
    for (int i = 0; i < 8; ++i) {
        int n = row0 + nb + i;
        if (n < nrows) {
#pragma unroll
            for (int j = 0; j < 8; ++j) {
                int d = cg + 16 * j;
                out[(size_t)n * 128 + d] = acc[i][j] + bias[d];
            }
        }
    }
}

// ---------- fused gather(LDS) + MFMA semantic-score GEMM (fp8 table) ----------
// fp8 e4m3 h-row = 128 B = ONE cache line per edge (halves the random-line
// L2-miss traffic vs fp16, the measured ~750 GB/s ceiling). Lane l owns dims
// [l*16, l*16+16) = one 16B load. Score error averages out over 100K nodes.
// 2-wide edge unroll (round-8 lesson: 4-wide kills occupancy).
__global__ __launch_bounds__(256) void fused_score2(
    const int* __restrict__ rowptr, const int2* __restrict__ es,
    const unsigned char* __restrict__ h8,
    const unsigned short* __restrict__ kw16, const float* __restrict__ kb,
    const float* __restrict__ q, float* __restrict__ scorebuf)
{
    __shared__ unsigned short Os[64][136];   // 17.4 KB; 272 B rows (fp16)
    __shared__ float redbuf[4];
    const int t = threadIdx.x;
    const int r = blockIdx.y;
    const int row0 = blockIdx.x * 64;        // grid.x 1563 -> 100032
    const int l = t & 7, ng = t >> 3;        // lane dim-slot / node group

#pragma unroll
    for (int pass = 0; pass < 2; ++pass) {
        int nl = pass * 32 + ng;
        int n = row0 + nl;
        float acc[16];
#pragma unroll
        for (int i = 0; i < 16; ++i) acc[i] = 0.f;
        if (n < NN) {
            int g = r * NN + n;
            int p0 = rowptr[g], p1 = rowptr[g + 1];
            int e = p0;
            for (; e + 1 < p1; e += 2) {
                int2 ea = es[e], eb = es[e + 1];
                float aa = __int_as_float(ea.y), ab = __int_as_float(eb.y);
                uint4 va = *(const uint4*)(h8 + (size_t)ea.x * 128 + l * 16);
                uint4 vb = *(const uint4*)(h8 + (size_t)eb.x * 128 + l * 16);
                const unsigned* wa = (const unsigned*)&va;
                const unsigned* wb = (const unsigned*)&vb;
#pragma unroll
                for (int w = 0; w < 4; ++w)
#pragma unroll
                    for (int b = 0; b < 4; ++b)
                        acc[w * 4 + b] += aa * fp8dec((wa[w] >> (8 * b)) & 0xFF)
                                        + ab * fp8dec((wb[w] >> (8 * b)) & 0xFF);
            }
            if (e < p1) {
                int2 ea = es[e];
                float aa = __int_as_float(ea.y);
                uint4 va = *(const uint4*)(h8 + (size_t)ea.x * 128 + l * 16);
                const unsigned* wa = (const unsigned*)&va;
#pragma unroll
                for (int w = 0; w < 4; ++w)
#pragma unroll
                    for (int b = 0; b < 4; ++b)
                        acc[w * 4 + b] += aa * fp8dec((wa[w] >> (8 * b)) & 0xFF);
            }
        }
        unsigned short ov[16];
#pragma unroll
        for (int i = 0; i < 16; ++i) ov[i] = f2h(fmaxf(acc[i], 0.f));  // relu
        // lane l owns dims [l*16, l*16+16): dim-major Os row
        *(short8*)&Os[nl][l * 16]     = *(short8*)&ov[0];
        *(short8*)&Os[nl][l * 16 + 8] = *(short8*)&ov[8];
    }
    __syncthreads();

    // MFMA (f16): wave w owns rows w*16..w*16+15. A[m=lane&15][k=quad*8+j]
    // (m89 layout, shape-determined); C/D: col=lane&15, row=quad*4+reg.
    const int wave = t >> 6, lane = t & 63;
    const int quad = lane >> 4, l16 = lane & 15;
    half8 a[4];
#pragma unroll
    for (int kc = 0; kc < 4; ++kc)
        a[kc] = *(const half8*)&Os[wave * 16 + l16][quad * 8 + kc * 32];

    float s = 0.f;
#pragma unroll
    for (int dt = 0; dt < 8; ++dt) {
        const unsigned short* brow = kw16 + (size_t)(dt * 16 + l16) * 128 + quad * 8;
        floatx4 accv = {0.f, 0.f, 0.f, 0.f};
#pragma unroll
        for (int kc = 0; kc < 4; ++kc) {
            half8 b = *(const half8*)(brow + kc * 32);
            accv = __builtin_amdgcn_mfma_f32_16x16x32_f16(a[kc], b, accv, 0, 0, 0);
        }
        int d = dt * 16 + l16;
        float kbv = kb[d], qv = q[d];
#pragma unroll
        for (int reg = 0; reg < 4; ++reg) {
            int node = row0 + wave * 16 + quad * 4 + reg;
            if (node < NN) {
                float y = accv[reg] + kbv;
                float e2 = __expf(2.f * y);
                float tn = 1.f - 2.f * __builtin_amdgcn_rcpf(e2 + 1.f);   // tanh
                s += tn * qv;
            }
        }
    }
    for (int off = 32; off > 0; off >>= 1) s += __shfl_down(s, off);
    if (lane == 0) redbuf[wave] = s;
    __syncthreads();
    if (t == 0) atomicAdd(scorebuf + r * 64 + (blockIdx.x & 63),
                          redbuf[0] + redbuf[1] + redbuf[2] + redbuf[3]);
}

// ---------- reduce 64 score partials per relation (1 wave) ----------
__global__ void score_reduce(const float* __restrict__ scorebuf, float* __restrict__ score) {
    int t = threadIdx.x;              // <<<1, 64>>>
    int r = t >> 3, k = t & 7;
    float v = 0.f;
#pragma unroll
    for (int i = 0; i < 8; ++i) v += scorebuf[r * 64 + k * 8 + i];
    v += __shfl_down(v, 4);
    v += __shfl_down(v, 2);
    v += __shfl_down(v, 1);
    if (k == 0) score[r] = v;
}

// ---------- per-node attention logits + fused fp16 + fp8 h emit ----------
__global__ __launch_bounds__(256) void att_kernel(
    const float* __restrict__ h, const float* __restrict__ asrc_w,
    const float* __restrict__ adst_w, float* __restrict__ a_src,
    float* __restrict__ a_dst, unsigned short* __restrict__ h16,
    unsigned char* __restrict__ h8)
{
    __shared__ float hs[16][128];
    int n0 = blockIdx.x * 16;
#pragma unroll
    for (int i = 0; i < 2; ++i) {
        int fi = threadIdx.x + i * 256;
        int n = fi >> 5, kq = fi & 31;
        float4 v = make_float4(0.f, 0.f, 0.f, 0.f);
        if (n0 + n < NN) v = *(const float4*)(h + (size_t)(n0 + n) * 128 + kq * 4);
        *(float4*)&hs[n][kq * 4] = v;
    }
    __syncthreads();
    int n = threadIdx.x >> 4, rr = threadIdx.x & 15;
    int r = rr & 7; int isd = rr >> 3;
    const float* w = (isd ? adst_w : asrc_w) + r * 128;
    float acc = 0.f;
#pragma unroll
    for (int kq = 0; kq < 32; ++kq) {
        float4 hv = *(const float4*)&hs[n][kq * 4];
        float4 wv = ((const float4*)w)[kq];
        acc += hv.x * wv.x + hv.y * wv.y + hv.z * wv.z + hv.w * wv.w;
    }
    if (n0 + n < NN) (isd ? a_dst : a_src)[r * NN + n0 + n] = acc;

    // emit fp16 + fp8 copies of this node tile (h already staged in LDS)
    int dq = rr * 8;
    if (n0 + n < NN) {
        unsigned short ov[8];
        unsigned lo = 0, hi = 0;
#pragma unroll
        for (int k = 0; k < 8; ++k) {
            float f = hs[n][dq + k];
            ov[k] = f2h(f);
            unsigned b = fp8enc(f);
            if (k < 4) lo |= b << (8 * k); else hi |= b << (8 * (k - 4));
        }
        *(short8*)(h16 + (size_t)(n0 + n) * 128 + dq) = *(short8*)ov;
        *(uint2*)(h8 + (size_t)(n0 + n) * 128 + dq) = make_uint2(lo, hi);
    }
}

// ---------- CSR segment softmax (PyG semantics, +1e-16); alpha -> es[].y ----------
// deg<=16: fully-unrolled predicated register pass (independent gathers,
// static indices -> VGPRs; bit-identical to 3-pass). deg>16: fallback.
__global__ void softmax_csr(const int* __restrict__ rowptr, int2* __restrict__ es,
                            const float* __restrict__ a_src, const float* __restrict__ a_dst)
{
    int g = blockIdx.x * 256 + threadIdx.x;
    if (g >= NSEG) return;
    int p0 = rowptr[g], p1 = rowptr[g + 1];
    int deg = p1 - p0;
    if (deg == 0) return;
    int r = g / NN;
    float ad = a_dst[g];
    const float* as = a_src + (size_t)r * NN;
    if (deg <= 16) {
        float lg[16];
        float m = -1e30f;
#pragma unroll
        for (int i = 0; i < 16; ++i) {
            if (i < deg) {
                float l = as[es[p0 + i].x] + ad;
                l = l > 0.f ? l : 0.2f * l;   // leaky_relu 0.2
                lg[i] = l;
                m = fmaxf(m, l);
            }
        }
        float ssum = 0.f;
#pragma unroll
        for (int i = 0; i < 16; ++i) {
            if (i < deg) { float ex = __expf(lg[i] - m); lg[i] = ex; ssum += ex; }
        }
        float inv = __builtin_amdgcn_rcpf(ssum + 1e-16f);
#pragma unroll
        for (int i = 0; i < 16; ++i) {
            if (i < deg) es[p0 + i].y = __float_as_int(lg[i] * inv);
        }
    } else {
        float m = -1e30f;
        for (int i = p0; i < p1; ++i) {
            float l = as[es[i].x] + ad;
            l = l > 0.f ? l : 0.2f * l;
            es[i].y = __float_as_int(l);
            m = fmaxf(m, l);
        }
        float s = 0.f;
        for (int k = p0; k < p1; ++k) {
            float e = __expf(__int_as_float(es[k].y) - m);
            es[k].y = __float_as_int(e);
            s += e;
        }
        float inv = __builtin_amdgcn_rcpf(s + 1e-16f);
        for (int k = p0; k < p1; ++k)
            es[k].y = __float_as_int(__int_as_float(es[k].y) * inv);
    }
}

// ---------- combine: fp16 gather (round-7 proven), fp32 accumulate ----------
// Full-line: lane (o = L&7) reads 16B at dims [o*8,+8) (line 0) and [64+o*8,+8)
// (line 1) -- each 128B line requested exactly once per edge. 2-wide unroll.
__global__ __launch_bounds__(256) void combine_csr(
    const int* __restrict__ rowptr, const int2* __restrict__ es,
    const unsigned short* __restrict__ h16, const float* __restrict__ score,
    float* __restrict__ comb)
{
    __shared__ float attn[NR];
    __shared__ float lds[4][64][17];          // 17.4 KB
    int t = threadIdx.x;
    if (t == 0) {
        float sc[NR]; float m = -1e30f;
        for (int r = 0; r < NR; ++r) { sc[r] = score[r] * (1.0f / NN); m = fmaxf(m, sc[r]); }
        float den = 0.f;
        for (int r = 0; r < NR; ++r) { sc[r] = __expf(sc[r] - m); den += sc[r]; }
        for (int r = 0; r < NR; ++r) attn[r] = sc[r] / den;
    }
    __syncthreads();

    int nl = t >> 6;
    int n = blockIdx.x * 4 + nl;              // grid 25000 -> n < 100000 exactly
    int L = t & 63;
    int r = L >> 3;
    int o = L & 7;                            // owns dims [o*8,+8) and [64+o*8,+8)
    float a[16];
#pragma unroll
    for (int i = 0; i < 16; ++i) a[i] = 0.f;
    {
        int g = r * NN + n;
        int p0 = rowptr[g], p1 = rowptr[g + 1];
        int e = p0;
        for (; e + 1 < p1; e += 2) {
            int2 ea = es[e], eb = es[e + 1];
            float aa = __int_as_float(ea.y), ab = __int_as_float(eb.y);
            const unsigned short* hpa = h16 + (size_t)ea.x * 128;
            const unsigned short* hpb = h16 + (size_t)eb.x * 128;
            short8 u0 = *(const short8*)(hpa + o * 8);
            short8 u1 = *(const short8*)(hpa + 64 + o * 8);
            short8 v0 = *(const short8*)(hpb + o * 8);
            short8 v1 = *(const short8*)(hpb + 64 + o * 8);
#pragma unroll
            for (int i = 0; i < 8; ++i) {
                a[i]     += aa * h2f((unsigned short)u0[i]) + ab * h2f((unsigned short)v0[i]);
                a[8 + i] += aa * h2f((unsigned short)u1[i]) + ab * h2f((unsigned short)v1[i]);
            }
        }
        if (e < p1) {
            int2 ea = es[e];
            float aa = __int_as_float(ea.y);
            const unsigned short* hpa = h16 + (size_t)ea.x * 128;
            short8 u0 = *(const short8*)(hpa + o * 8);
            short8 u1 = *(const short8*)(hpa + 64 + o * 8);
#pragma unroll
            for (int i = 0; i < 8; ++i) {
                a[i]     += aa * h2f((unsigned short)u0[i]);
                a[8 + i] += aa * h2f((unsigned short)u1[i]);
            }
        }
    }
    float w = attn[r];
    float* dst = &lds[nl][L][0];
#pragma unroll
    for (int i = 0; i < 16; ++i) dst[i] = w * fmaxf(a[i], 0.f);   // relu per (n,r)
    __syncthreads();

    // phase 2: sum over relations. Lane (r,o) slot s holds dim o*8+s (s<8) or
    // 64+o*8+(s-8) (s>=8). Thread L writes dims d0=2L, d0+1 (same o, s pair).
    int d0 = 2 * L;
    int o2, s0;
    if (d0 < 64) { o2 = d0 >> 3; s0 = d0 & 7; }
    else         { o2 = (d0 - 64) >> 3; s0 = 8 + ((d0 - 64) & 7); }
    float x0 = 0.f, x1 = 0.f;
#pragma unroll
    for (int rr = 0; rr < NR; ++rr) {
        x0 += lds[nl][rr * 8 + o2][s0];
        x1 += lds[nl][rr * 8 + o2][s0 + 1];
    }
    *(float2*)(comb + (size_t)n * 128 + d0) = make_float2(x0, x1);
}

// ---------- link head ----------
__global__ __launch_bounds__(256) void head_kernel(
    const float* __restrict__ hfin, const int* __restrict__ eli,
    const float* __restrict__ pw, const float* __restrict__ pb,
    float* __restrict__ out)
{
    int t = threadIdx.x;
    int l = blockIdx.x * 4 + (t >> 6);        // grid 32768 -> l < 131072 exactly
    int d0 = (t & 63) * 2;
    int a = eli[l], b = eli[NL + l];
    float2 ha = *(const float2*)(hfin + (size_t)a * 128 + d0);
    float2 hb = *(const float2*)(hfin + (size_t)b * 128 + d0);
    float w0 = pw[d0 * 2] + pw[d0 * 2 + 1];
    float w1 = pw[d0 * 2 + 2] + pw[d0 * 2 + 3];
    float v = ha.x * hb.x * w0 + ha.y * hb.y * w1;
    for (int off = 32; off > 0; off >>= 1) v += __shfl_down(v, off);
    if ((t & 63) == 0) out[l] = v + pb[0] + pb[1];
}

extern "C" void kernel_launch(void* const* d_in, const int* in_sizes, int n_in,
                              void* d_out, int out_size, void* d_ws, size_t ws_size,
                              hipStream_t stream)
{
    const float* x     = (const float*)d_in[0];
    const int*   ei    = (const int*)d_in[1];
    const int*   eli   = (const int*)d_in[2];
    const float* w1    = (const float*)d_in[3];
    const float* b1    = (const float*)d_in[4];
    const float* asrc1 = (const float*)d_in[5];
    const float* adst1 = (const float*)d_in[6];
    const float* q1    = (const float*)d_in[7];
    const float* kw1   = (const float*)d_in[8];
    const float* kb1   = (const float*)d_in[9];
    const float* w2    = (const float*)d_in[10];
    const float* b2    = (const float*)d_in[11];
    const float* asrc2 = (const float*)d_in[12];
    const float* adst2 = (const float*)d_in[13];
    const float* q2    = (const float*)d_in[14];
    const float* kw2   = (const float*)d_in[15];
    const float* kb2   = (const float*)d_in[16];
    const float* pw    = (const float*)d_in[17];
    const float* pb    = (const float*)d_in[18];
    float* out = (float*)d_out;

    // ---- workspace layout (float offsets); total ~128.2 MB (proven size) ----
    float* ws      = (float*)d_ws;
    float* hA      = ws;                         // 12,800,000
    float* hB      = ws + 12800000ull;           // 12,800,000
    float* a_src   = ws + 25600000ull;           // 800,000
    float* a_dst   = ws + 26400000ull;           // 800,000
    int2*  es      = (int2*)(ws + 27200000ull);  // 1,600,000 x int2 (src, alpha)
    int*   rowptr  = (int*)(ws + 30400000ull);   // 800,768 (padded)
    int*   counts  = (int*)(ws + 31200768ull);   // 800,768 (padded; reused as cursor)
    int*   bsums   = (int*)(ws + 32001536ull);   // 1,024
    float* score   = ws + 32002560ull;           // 64
    float* wt      = ws + 32002624ull;           // 16,384
    unsigned short* kw16 = (unsigned short*)(ws + 32019008ull);  // 16,384 ushorts
    // scorebuf (512 floats) aliases counts: counts/cursor dead after fill_kernel
    float* scorebuf = (float*)counts;
    // Per layer, the 51.2MB non-H buffer holds: h16 (25.6MB) then h8 (12.8MB)
    // -- both fit with 12.8MB spare; all within the proven 128.2MB footprint.
    //   L0: gemm x->hA;  h16/h8 in hB;  comb -> hA
    //   L1: gemm hA->hB; h16/h8 in hA (comb0 dead after gemm); comb -> hB
    // head reads hB.

    // ---- CSR build (edge_index is layer-invariant: build once) ----
    hipMemsetAsync(counts, 0, NPAD * sizeof(int), stream);
    hist_kernel<<<6250, 256, 0, stream>>>(ei, counts);
    scan_k1<<<NB_SCAN, 256, 0, stream>>>(counts, rowptr, bsums);
    scan_k2<<<1, 256, 0, stream>>>(bsums, NB_SCAN);
    scan_k3<<<3126, 256, 0, stream>>>(rowptr, bsums);
    hipMemsetAsync(counts, 0, NPAD * sizeof(int), stream);
    fill_kernel<<<6250, 256, 0, stream>>>(ei, rowptr, counts, (int*)es);

    for (int layer = 0; layer < 2; ++layer) {
        const float* Ain  = layer ? hA : x;
        float*       H    = layer ? hB : hA;
        unsigned short* h16 = (unsigned short*)(layer ? hA : hB);
        unsigned char*  h8  = (unsigned char*)(h16 + 12800000ull);
        const float* W    = layer ? w2 : w1;
        const float* bb   = layer ? b2 : b1;
        const float* as_w = layer ? asrc2 : asrc1;
        const float* ad_w = layer ? adst2 : adst1;
        const float* qq   = layer ? q2 : q1;
        const float* kw   = layer ? kw2 : kw1;
        const float* kb   = layer ? kb2 : kb1;

        transpose128<<<64, 256, 0, stream>>>(W, wt);
        gemm_proj<<<782, 256, 0, stream>>>(Ain, wt, bb, H, NN);
        cast_f16<<<16, 256, 0, stream>>>(kw, kw16);
        att_kernel<<<6250, 256, 0, stream>>>(H, as_w, ad_w, a_src, a_dst, h16, h8);
        softmax_csr<<<3125, 256, 0, stream>>>(rowptr, es, a_src, a_dst);
        hipMemsetAsync(scorebuf, 0, 512 * sizeof(float), stream);
        fused_score2<<<dim3(1563, NR), 256, 0, stream>>>(rowptr, es, h8,
                                                         kw16, kb, qq, scorebuf);
        score_reduce<<<1, 64, 0, stream>>>(scorebuf, score);
        combine_csr<<<25000, 256, 0, stream>>>(rowptr, es, h16, score, H);
        // H now holds this layer's output embeddings (comb)
    }
    head_kernel<<<32768, 256, 0, stream>>>(hB, eli, pw, pb, out);
}